// Round 5
// baseline (246.144 us; speedup 1.0000x reference)
//
#include <hip/hip_runtime.h>

#define B_ROWS 14336
#define D_DIM  512
#define C_CLS  7
#define M_CLS  2048

typedef __attribute__((ext_vector_type(4))) float f32x4;

// fp8 scale: fea*64 -> sigma~3.2 in e4m3 range; Gram scaled by 4096
#define FP8_SCALE 64.0f
#define INV_2S2   (2.0f / 4096.0f)

typedef const __attribute__((address_space(1))) char gchar_t;
typedef __attribute__((address_space(3))) char lchar_t;

__device__ __forceinline__ void gload16(const char* g, char* l) {
  // async global->LDS DMA, 16B/lane, dest = wave-uniform base + lane*16
  __builtin_amdgcn_global_load_lds((gchar_t*)g, (lchar_t*)l, 16, 0, 0);
}

// K0: fea->fp8 packed in fragment-order image + row norms + logits + zero zb.
// Image layout (direct-load coalesced MFMA fragments): 16B at
// (r16, kp, l) = byte offset ((r16*8 + kp)*64 + l)*16, holding row
// r16*16 + (l&15), bytes {kp*64 + (l>>4)*8 ..+7} (lo) and {+32 ..} (hi).
__global__ __launch_bounds__(256) void k_prep(const float* __restrict__ fea,
                                              const float* __restrict__ W,
                                              char* __restrict__ f8p,
                                              float* __restrict__ an,
                                              float* __restrict__ logits,
                                              float* __restrict__ zb) {  // 64 floats
  int t = threadIdx.x, wave = t >> 6, lane = t & 63;
  if (blockIdx.x == 0 && t < 64) zb[t] = 0.f;
  __shared__ char lrow[16 * 528];  // 16 rows x 512B fp8 (+16 pad)

  int r0 = blockIdx.x * 16;
#pragma unroll
  for (int k = 0; k < 4; ++k) {
    int rl = wave * 4 + k;
    int row = r0 + rl;
    const float4* fr4 = (const float4*)(fea + (size_t)row * D_DIM);
    float4 v0 = fr4[lane * 2], v1 = fr4[lane * 2 + 1];
    float s = v0.x * v0.x + v0.y * v0.y + v0.z * v0.z + v0.w * v0.w +
              v1.x * v1.x + v1.y * v1.y + v1.z * v1.z + v1.w * v1.w;
#pragma unroll
    for (int o = 1; o < 64; o <<= 1) s += __shfl_xor(s, o);
    if (lane == 0) an[row] = s;
    int w0 = __builtin_amdgcn_cvt_pk_fp8_f32(v0.x * FP8_SCALE, v0.y * FP8_SCALE, 0, 0);
    w0     = __builtin_amdgcn_cvt_pk_fp8_f32(v0.z * FP8_SCALE, v0.w * FP8_SCALE, w0, 1);
    int w1 = __builtin_amdgcn_cvt_pk_fp8_f32(v1.x * FP8_SCALE, v1.y * FP8_SCALE, 0, 0);
    w1     = __builtin_amdgcn_cvt_pk_fp8_f32(v1.z * FP8_SCALE, v1.w * FP8_SCALE, w1, 1);
    *(int2*)&lrow[rl * 528 + lane * 8] = make_int2(w0, w1);
#pragma unroll
    for (int c = 0; c < 7; ++c) {
      const float4* w4 = (const float4*)(W + c * D_DIM);
      float4 q0 = w4[lane * 2], q1 = w4[lane * 2 + 1];
      float p = v0.x * q0.x + v0.y * q0.y + v0.z * q0.z + v0.w * q0.w +
                v1.x * q1.x + v1.y * q1.y + v1.z * q1.z + v1.w * q1.w;
#pragma unroll
      for (int o = 1; o < 64; o <<= 1) p += __shfl_xor(p, o);
      if (lane == 0) logits[row * 7 + c] = p;
    }
  }
  __syncthreads();
  // image write-out: 512 16B chunks/block, coalesced
  int4* outp = (int4*)f8p + (size_t)blockIdx.x * 512;
#pragma unroll
  for (int pi = 0; pi < 2; ++pi) {
    int idx = pi * 256 + t;          // [0,512) = (kp, l)
    int kp = idx >> 6, l = idx & 63;
    int sr = l & 15, qk = l >> 4;
    int2 lo = *(const int2*)&lrow[sr * 528 + kp * 64 + qk * 8];
    int2 hi = *(const int2*)&lrow[sr * 528 + kp * 64 + 32 + qk * 8];
    outp[idx] = make_int4(lo.x, lo.y, hi.x, hi.y);
  }
}

// K1 v4: block = 4 waves sharing one 32-row A-panel in LDS (staged ONCE per
// block via global_load_lds -> ONE barrier per block, unlike round-0's
// per-K-step drains). Wave w owns 32x32 tile (ti, tj0+w), streaming only B:
// 4 named reg buffers, prologue kp0-3 issued BEFORE the stage barrier,
// reloads at 4-phase lookahead (~600cy). A-frags via stride-1 ds_read_b128
// (conflict-free, all-immediate offsets); B offsets fold into the 13-bit imm
// via pre-bumped pointers -> near-zero per-phase address VALU.
// Round-3 postmortem: occupancy 1.7x moved time only -9% -> bound by the
// per-wave load stream (L1 delivery + addr VALU + shallow lookahead), which
// this round halves (32->16 loads/tile) and deepens (1->4 phase lookahead).
// Jobs: row strips of 4 tiles. self: 544 strips/class (exact triangle,
// strip k has rows ti in [4k,64), cum C(k)=66k-2k^2); cross: 64x16=1024/pair.
// Grid 9968 = 1246 u x 8 xcd:
//   xcd<7 : u<544 self class=xcd; u in [544,1246): cross ci = xcd*702+(u-544)
//   xcd==7: u<1230 cross ci = 4914+u; u in [1230,1244): BN waves; else idle
__global__ __launch_bounds__(256, 5) void k_gram(const char* __restrict__ f8p,
                                                 const float* __restrict__ an,
                                                 const float* __restrict__ logits,
                                                 float* __restrict__ S,
                                                 float* __restrict__ rs_part,
                                                 float* __restrict__ S1,
                                                 float* __restrict__ S2,
                                                 float* __restrict__ aff) {
  int xcd = blockIdx.x & 7, u = blockIdx.x >> 3;
  int t = threadIdx.x, lane = t & 63, wave = t >> 6;
  if (blockIdx.x == 0 && t == 0) aff[0] = 0.f;
  __shared__ char ldsA[16384];
  __shared__ float bacc[4];

  int c1, c2, ti, tj0, Sidx;
  bool self;
  if (xcd < 7) {
    if (u < 544) {                       // self strips, class = xcd
      int k = 0;
      while (u >= 66 * (k + 1) - 2 * (k + 1) * (k + 1)) ++k;  // <=16 iters
      ti = 4 * k + (u - (66 * k - 2 * k * k));
      tj0 = 4 * k;
      c1 = xcd; c2 = xcd; Sidx = xcd; self = true;
    } else {
      int ci = xcd * 702 + (u - 544);    // 0..4913
      int p = ci >> 10, tt = ci & 1023;
      ti = tt >> 4; tj0 = (tt & 15) << 2;
      c1 = p + 1; c2 = 0; Sidx = 7 + p; self = false;
    }
  } else {
    if (u < 1230) {
      int ci = 4914 + u;                 // 4914..6143
      int p = ci >> 10, tt = ci & 1023;
      ti = tt >> 4; tj0 = (tt & 15) << 2;
      c1 = p + 1; c2 = 0; Sidx = 7 + p; self = false;
    } else if (u < 1244) {
      // BN stats, wave-level: 56 jobs = (class, 1792-row segment)
      int idx = (u - 1230) * 4 + wave;   // 0..55
      int c = idx >> 3, seg = idx & 7;
      int r0 = seg * 1792;
      float s1 = 0.f, s2 = 0.f;
      for (int j = lane; j < 1792; j += 64) {
        float v = logits[(size_t)(r0 + j) * 7 + c];
        s1 += v;
        s2 += v * v;
      }
#pragma unroll
      for (int o = 1; o < 64; o <<= 1) {
        s1 += __shfl_xor(s1, o);
        s2 += __shfl_xor(s2, o);
      }
      if (lane == 0) { atomicAdd(&S1[c], s1); atomicAdd(&S2[c], s2); }
      return;
    } else return;
  }

  int tj = tj0 + wave;
  bool valid = (!self) || (tj <= ti);
  int R0 = c1 * M_CLS + ti * 32;
  int C0 = c2 * M_CLS + tj * 32;

  // B prologue (kp 0..3) + row norms: issued BEFORE the stage barrier so
  // their latency hides under the A-panel DMA. tj<=63 always -> in-bounds.
  const char* pB0 = f8p + ((size_t)(C0 >> 4) << 13) + lane * 16;
  const char* pB1 = pB0 + 8192;
  longlong2 b0[2], b1[2], b2[2], b3[2];
  b0[0] = *(const longlong2*)(pB0);        b0[1] = *(const longlong2*)(pB1);
  b1[0] = *(const longlong2*)(pB0 + 1024); b1[1] = *(const longlong2*)(pB1 + 1024);
  b2[0] = *(const longlong2*)(pB0 + 2048); b2[1] = *(const longlong2*)(pB1 + 2048);
  b3[0] = *(const longlong2*)(pB0 + 3072); b3[1] = *(const longlong2*)(pB1 + 3072);

  int q = lane >> 4, s = lane & 15;
  f32x4 anA[2];
  float anB[2];
  anA[0] = *(const f32x4*)&an[R0 + q * 4];
  anA[1] = *(const f32x4*)&an[R0 + 16 + q * 4];
  anB[0] = an[C0 + s];
  anB[1] = an[C0 + 16 + s];

  // Stage shared A panel (32 rows = 16 KB, contiguous in image) to LDS.
  {
    const char* pA = f8p + ((size_t)(R0 >> 4) << 13);
    int ch = wave * 4;
    gload16(pA + (size_t)(ch + 0) * 1024 + lane * 16, &ldsA[(ch + 0) * 1024 + lane * 16]);
    gload16(pA + (size_t)(ch + 1) * 1024 + lane * 16, &ldsA[(ch + 1) * 1024 + lane * 16]);
    gload16(pA + (size_t)(ch + 2) * 1024 + lane * 16, &ldsA[(ch + 2) * 1024 + lane * 16]);
    gload16(pA + (size_t)(ch + 3) * 1024 + lane * 16, &ldsA[(ch + 3) * 1024 + lane * 16]);
  }
  __syncthreads();   // one DMA drain per BLOCK (not per K-step)

  f32x4 acc[2][2];
#pragma unroll
  for (int i = 0; i < 2; ++i)
#pragma unroll
    for (int j = 0; j < 2; ++j)
      acc[i][j] = (f32x4){0.f, 0.f, 0.f, 0.f};
  float blockAcc = 0.f;

  if (valid) {
    const char* rB0 = pB0 + 4096;   // reload bases: offsets stay in imm field
    const char* rB1 = pB1 + 4096;
    unsigned ab = (unsigned)(lane * 16);
    longlong2 a0, a1;

#define MM(b_)                                                                 \
    do {                                                                       \
      __builtin_amdgcn_s_setprio(1);                                          \
      acc[0][0] = __builtin_amdgcn_mfma_f32_16x16x32_fp8_fp8(a0.x, b_[0].x, acc[0][0], 0, 0, 0); \
      acc[0][1] = __builtin_amdgcn_mfma_f32_16x16x32_fp8_fp8(a0.x, b_[1].x, acc[0][1], 0, 0, 0); \
      acc[1][0] = __builtin_amdgcn_mfma_f32_16x16x32_fp8_fp8(a1.x, b_[0].x, acc[1][0], 0, 0, 0); \
      acc[1][1] = __builtin_amdgcn_mfma_f32_16x16x32_fp8_fp8(a1.x, b_[1].x, acc[1][1], 0, 0, 0); \
      acc[0][0] = __builtin_amdgcn_mfma_f32_16x16x32_fp8_fp8(a0.y, b_[0].y, acc[0][0], 0, 0, 0); \
      acc[0][1] = __builtin_amdgcn_mfma_f32_16x16x32_fp8_fp8(a0.y, b_[1].y, acc[0][1], 0, 0, 0); \
      acc[1][0] = __builtin_amdgcn_mfma_f32_16x16x32_fp8_fp8(a1.y, b_[0].y, acc[1][0], 0, 0, 0); \
      acc[1][1] = __builtin_amdgcn_mfma_f32_16x16x32_fp8_fp8(a1.y, b_[1].y, acc[1][1], 0, 0, 0); \
      __builtin_amdgcn_s_setprio(0);                                          \
    } while (0)
#define DSA(kpo_)                                                              \
    do {                                                                       \
      a0 = *(const longlong2*)&ldsA[ab + (kpo_) * 1024];                       \
      a1 = *(const longlong2*)&ldsA[ab + 8192 + (kpo_) * 1024];                \
    } while (0)

#pragma unroll 1
    for (int h = 0; h < 2; ++h) {
      DSA(0); MM(b0);
      if (h == 0) { b0[0] = *(const longlong2*)(rB0);        b0[1] = *(const longlong2*)(rB1); }
      DSA(1); MM(b1);
      if (h == 0) { b1[0] = *(const longlong2*)(rB0 + 1024); b1[1] = *(const longlong2*)(rB1 + 1024); }
      DSA(2); MM(b2);
      if (h == 0) { b2[0] = *(const longlong2*)(rB0 + 2048); b2[1] = *(const longlong2*)(rB1 + 2048); }
      DSA(3); MM(b3);
      if (h == 0) { b3[0] = *(const longlong2*)(rB0 + 3072); b3[1] = *(const longlong2*)(rB1 + 3072); }
      ab += 4096;
    }
#undef DSA
#undef MM

    // Epilogue. C/D layout (16x16x32): col=lane&15, row=(lane>>4)*4+reg.
    bool mirror = self && (ti > tj);
    bool diag = self && (ti == tj);
    float colAcc[2] = {0.f, 0.f};
#pragma unroll
    for (int mi = 0; mi < 2; ++mi) {
#pragma unroll
      for (int rg = 0; rg < 4; ++rg) {
        int rl = mi * 16 + q * 4 + rg;
        float aA = anA[mi][rg];
        float rowAcc = 0.f;
#pragma unroll
        for (int mj = 0; mj < 2; ++mj) {
          int cl = mj * 16 + s;
          float g = acc[mi][mj][rg];
          float d2 = fmaxf(aA + anB[mj] - g * INV_2S2, 0.f);
          if (diag && rl == cl) d2 = 0.f;  // exact diagonal
          float e1 = __expf(-0.05f * d2);
          float e2 = e1 * e1, e4 = e2 * e2, e8 = e4 * e4, e16 = e8 * e8;
          blockAcc += e1 + e2 + e4 + e8 + e16;
          if (self) {
            float ek = __expf(-12.5f * d2);  // KDE: 1/(2*0.2^2)
            rowAcc += ek;
            if (mirror) colAcc[mj] += ek;
          }
        }
        if (self) {
          rowAcc += __shfl_xor(rowAcc, 1);
          rowAcc += __shfl_xor(rowAcc, 2);
          rowAcc += __shfl_xor(rowAcc, 4);
          rowAcc += __shfl_xor(rowAcc, 8);
          if (s == 0) rs_part[(size_t)(R0 + rl) * 64 + tj] = rowAcc;
        }
      }
    }
    if (mirror) {
#pragma unroll
      for (int mj = 0; mj < 2; ++mj) {
        float v = colAcc[mj];
        v += __shfl_xor(v, 16);
        v += __shfl_xor(v, 32);
        if (q == 0)
          rs_part[(size_t)(C0 + mj * 16 + s) * 64 + ti] = v;
      }
      blockAcc *= 2.f;  // mirror tile counted once
    }
#pragma unroll
    for (int o = 1; o < 64; o <<= 1) blockAcc += __shfl_xor(blockAcc, o);
  }

  // block-level reduce: all 4 waves share Sidx; invalid waves contribute 0
  if (lane == 0) bacc[wave] = blockAcc;
  __syncthreads();
  if (t == 0) atomicAdd(&S[Sidx], bacc[0] + bacc[1] + bacc[2] + bacc[3]);
}

// K2: bnout (blocks 0..97, 1024 thr) + per-class KDE weight & affinity
// (blocks 98..104). aff zeroed in k_gram.
__global__ __launch_bounds__(1024) void k_final(const float* __restrict__ logits,
                                                const float* __restrict__ S1,
                                                const float* __restrict__ S2,
                                                const float* __restrict__ gamma,
                                                const float* __restrict__ beta,
                                                const float* __restrict__ rs_part,
                                                const float* __restrict__ S,
                                                float* __restrict__ out) {
  int b = blockIdx.x, t = threadIdx.x;
  if (b < 98) {
    int idx = b * 1024 + t;  // 98*1024 = 100352 exactly
    int row = idx / 7;
    int c = idx - row * 7;
    float mu = S1[c] * (1.f / 14336.f);
    float var = S2[c] * (1.f / 14336.f) - mu * mu;
    out[idx] = gamma[c] * (logits[idx] - mu) * rsqrtf(var + 1e-5f) + beta[c];
    return;
  }
  int c = b - 98;
  // log_norm = -256*ln(2*pi*0.04) - ln(2048)
  const float LOG_NORM = 345.9110632f;
  float v = 0.f;
  for (int i = t; i < M_CLS; i += 1024) {
    const float4* rp = (const float4*)(rs_part + (size_t)(c * M_CLS + i) * 64);
    float rsum = 0.f;
#pragma unroll
    for (int jj = 0; jj < 16; ++jj) {
      float4 x = rp[jj];
      rsum += x.x + x.y + x.z + x.w;
    }
    v += 1.f / (logf(rsum) + LOG_NORM);
  }
#pragma unroll
  for (int o = 1; o < 64; o <<= 1) v += __shfl_xor(v, o);
  __shared__ float r[16];
  if ((t & 63) == 0) r[t >> 6] = v;
  __syncthreads();
  if (t == 0) {
    float vs = 0.f;
#pragma unroll
    for (int w = 0; w < 16; ++w) vs += r[w];
    float w = 1.f / (vs + 1e-5f);
    const float inv_m2 = 1.0f / ((float)M_CLS * (float)M_CLS);
    float Ssrc = S[c];
    float Stgt = (c > 0) ? S[0] : S[1];
    float X    = (c > 0) ? S[6 + c] : S[7];  // cross Sidx 7+p is (p+1,0); X01==X10
    float mmd = (Ssrc + Stgt - 2.f * X) * inv_m2;
    atomicAdd(&out[100352], -mmd * w);
  }
}

extern "C" void kernel_launch(void* const* d_in, const int* in_sizes, int n_in,
                              void* d_out, int out_size, void* d_ws, size_t ws_size,
                              hipStream_t stream) {
  const float* fea   = (const float*)d_in[0];
  const float* W_fc  = (const float*)d_in[1];
  const float* gamma = (const float*)d_in[2];
  const float* beta  = (const float*)d_in[3];
  float* out = (float*)d_out;

  char* ws = (char*)d_ws;
  char* f8p = ws;                                // packed fp8 image: 7,340,032 B
  float* fbase   = (float*)(ws + 7340032);
  float* an      = fbase;                        // 14336
  float* logits  = fbase + 14336;                // 100352
  float* zb      = fbase + 114688;               // 64-float zero block
  float* S1      = zb;                           //   [0..6]
  float* S2      = zb + 7;                       //   [7..13]
  float* S       = zb + 16;                      //   [16..28] (13 used)
  float* rs_part = fbase + 114752;               // 14336*64 row-major (fully written)

  k_prep <<<896,  256, 0, stream>>>(fea, W_fc, f8p, an, logits, zb);
  k_gram <<<9968, 256, 0, stream>>>(f8p, an, logits, S, rs_part, S1, S2,
                                    out + 100352);
  k_final<<<105, 1024, 0, stream>>>(logits, S1, S2, gamma, beta, rs_part, S, out);
}

// Round 6
// 240.694 us; speedup vs baseline: 1.0226x; 1.0226x over previous
//
#include <hip/hip_runtime.h>

#define B_ROWS 14336
#define D_DIM  512
#define C_CLS  7
#define M_CLS  2048

typedef __attribute__((ext_vector_type(4))) float f32x4;

// fp8 scale: fea*64 -> sigma~3.2 in e4m3 range; Gram scaled by 4096
#define FP8_SCALE 64.0f
#define INV_2S2   (2.0f / 4096.0f)

// K0: fea->fp8 packed in fragment-order image + row norms + logits + zero zb.
// Image layout (direct-load coalesced MFMA fragments): 16B at
// (r16, kp, l) = byte offset ((r16*8 + kp)*64 + l)*16, holding row
// r16*16 + (l&15), bytes {kp*64 + (l>>4)*8 ..+7} (lo) and {+32 ..} (hi).
// Reduction scheme (bit-identical tree to full butterfly): 8 values
// (7 logits + norm) reduced via xor1,2,4 (cheap DPP), then a cndmask
// select of value lane&7, then ONE xor8,16,32 finish -> the expensive
// cross-row permlane ops drop from 16/row to 2/row.
__global__ __launch_bounds__(256) void k_prep(const float* __restrict__ fea,
                                              const float* __restrict__ W,
                                              char* __restrict__ f8p,
                                              float* __restrict__ an,
                                              float* __restrict__ logits,
                                              float* __restrict__ zb) {  // 64 floats
  int t = threadIdx.x, wave = t >> 6, lane = t & 63;
  if (blockIdx.x == 0 && t < 64) zb[t] = 0.f;
  __shared__ char lrow[16 * 528];  // 16 rows x 512B fp8 (+16 pad)

  int r0 = blockIdx.x * 16;
#pragma unroll
  for (int k = 0; k < 4; ++k) {
    int rl = wave * 4 + k;
    int row = r0 + rl;
    const float4* fr4 = (const float4*)(fea + (size_t)row * D_DIM);
    float4 v0 = fr4[lane * 2], v1 = fr4[lane * 2 + 1];

    // 8 per-lane partials: p[0..6] = logits dots, p[7] = row norm
    float p[8];
#pragma unroll
    for (int c = 0; c < 7; ++c) {
      const float4* w4 = (const float4*)(W + c * D_DIM);
      float4 q0 = w4[lane * 2], q1 = w4[lane * 2 + 1];
      p[c] = v0.x * q0.x + v0.y * q0.y + v0.z * q0.z + v0.w * q0.w +
             v1.x * q1.x + v1.y * q1.y + v1.z * q1.z + v1.w * q1.w;
    }
    p[7] = v0.x * v0.x + v0.y * v0.y + v0.z * v0.z + v0.w * v0.w +
           v1.x * v1.x + v1.y * v1.y + v1.z * v1.z + v1.w * v1.w;

    // stage 1: xor 1,2,4 on all 8 (intra-8-lane groups, DPP-cheap)
#pragma unroll
    for (int c = 0; c < 8; ++c) {
      p[c] += __shfl_xor(p[c], 1);
      p[c] += __shfl_xor(p[c], 2);
      p[c] += __shfl_xor(p[c], 4);
    }
    // stage 2: lane picks value (lane&7), then xor 8,16,32 finish
    int v = lane & 7;
    float y = p[0];
    y = (v == 1) ? p[1] : y;
    y = (v == 2) ? p[2] : y;
    y = (v == 3) ? p[3] : y;
    y = (v == 4) ? p[4] : y;
    y = (v == 5) ? p[5] : y;
    y = (v == 6) ? p[6] : y;
    y = (v == 7) ? p[7] : y;
    y += __shfl_xor(y, 8);
    y += __shfl_xor(y, 16);
    y += __shfl_xor(y, 32);
    if (lane < 7) logits[row * 7 + lane] = y;
    else if (lane == 7) an[row] = y;

    int w0 = __builtin_amdgcn_cvt_pk_fp8_f32(v0.x * FP8_SCALE, v0.y * FP8_SCALE, 0, 0);
    w0     = __builtin_amdgcn_cvt_pk_fp8_f32(v0.z * FP8_SCALE, v0.w * FP8_SCALE, w0, 1);
    int w1 = __builtin_amdgcn_cvt_pk_fp8_f32(v1.x * FP8_SCALE, v1.y * FP8_SCALE, 0, 0);
    w1     = __builtin_amdgcn_cvt_pk_fp8_f32(v1.z * FP8_SCALE, v1.w * FP8_SCALE, w1, 1);
    *(int2*)&lrow[rl * 528 + lane * 8] = make_int2(w0, w1);
  }
  __syncthreads();
  // image write-out: 512 16B chunks/block, coalesced
  int4* outp = (int4*)f8p + (size_t)blockIdx.x * 512;
#pragma unroll
  for (int pi = 0; pi < 2; ++pi) {
    int idx = pi * 256 + t;          // [0,512) = (kp, l)
    int kp = idx >> 6, l = idx & 63;
    int sr = l & 15, qk = l >> 4;
    int2 lo = *(const int2*)&lrow[sr * 528 + kp * 64 + qk * 8];
    int2 hi = *(const int2*)&lrow[sr * 528 + kp * 64 + 32 + qk * 8];
    outp[idx] = make_int4(lo.x, lo.y, hi.x, hi.y);
  }
}

// K1: round-3's proven structure (barrier-free, LDS-free, 32x32 wave tiles,
// 2-buffer pipeline, no spill at 134.7us) with ONE mechanical fix: four
// advancing base pointers so every load's offset (0/1024/2048/3072) fits the
// 13-bit imm field (8192 didn't -> r3 paid ~2 VALU per load).
// Grid 10048 = 1256 u x 8 xcd, 256 thr (4 waves), every wave owns a tile:
//   xcd<7 : u<520 self class=xcd (job = u*4+wave in [0,2080))
//           u in [520,1256): cross cb = xcd*736 + (u-520)   (cb<5152)
//   xcd==7: u<992 cross cb = 5152+u; u in [992,1006): BN waves; else idle
__global__ __launch_bounds__(256, 5) void k_gram(const char* __restrict__ f8p,
                                                 const float* __restrict__ an,
                                                 const float* __restrict__ logits,
                                                 float* __restrict__ S,
                                                 float* __restrict__ rs_part,
                                                 float* __restrict__ S1,
                                                 float* __restrict__ S2,
                                                 float* __restrict__ aff) {
  int xcd = blockIdx.x & 7, u = blockIdx.x >> 3;
  int t = threadIdx.x, lane = t & 63, wave = t >> 6;
  if (blockIdx.x == 0 && t == 0) aff[0] = 0.f;
  __shared__ float bacc[4];

  int c1, c2, ti, tj, Sidx;
  bool self;
  if (xcd < 7) {
    if (u < 520) {                       // self triangle, class = xcd
      int job = u * 4 + wave;            // 0..2079
      int a = (int)((sqrtf(8.f * (float)job + 1.f) - 1.f) * 0.5f);
      if ((((a + 1) * (a + 2)) >> 1) <= job) ++a;   // fp guards
      if (((a * (a + 1)) >> 1) > job) --a;
      ti = a; tj = job - ((a * (a + 1)) >> 1);
      c1 = xcd; c2 = xcd; Sidx = xcd; self = true;
    } else {
      int cb = xcd * 736 + (u - 520);    // 0..5151
      int p = cb >> 10;
      int tile = ((cb & 1023) << 2) + wave;
      ti = tile >> 6; tj = tile & 63;
      c1 = p + 1; c2 = 0; Sidx = 7 + p; self = false;
    }
  } else {
    if (u < 992) {
      int cb = 5152 + u;                 // 5152..6143
      int p = cb >> 10;
      int tile = ((cb & 1023) << 2) + wave;
      ti = tile >> 6; tj = tile & 63;
      c1 = p + 1; c2 = 0; Sidx = 7 + p; self = false;
    } else if (u < 1006) {
      // BN stats, wave-level: 56 jobs = (class, 1792-row segment)
      int idx = (u - 992) * 4 + wave;    // 0..55
      int c = idx >> 3, seg = idx & 7;
      int r0 = seg * 1792;
      float s1 = 0.f, s2 = 0.f;
      for (int j = lane; j < 1792; j += 64) {
        float v = logits[(size_t)(r0 + j) * 7 + c];
        s1 += v;
        s2 += v * v;
      }
#pragma unroll
      for (int o = 1; o < 64; o <<= 1) {
        s1 += __shfl_xor(s1, o);
        s2 += __shfl_xor(s2, o);
      }
      if (lane == 0) { atomicAdd(&S1[c], s1); atomicAdd(&S2[c], s2); }
      return;
    } else return;
  }

  int R0 = c1 * M_CLS + ti * 32;
  int C0 = c2 * M_CLS + tj * 32;

  // row norms up-front (tiny, L2-hot; hides under K-loop)
  int q = lane >> 4, s = lane & 15;
  f32x4 anA[2];
  float anB[2];
  anA[0] = *(const f32x4*)&an[R0 + q * 4];
  anA[1] = *(const f32x4*)&an[R0 + 16 + q * 4];
  anB[0] = an[C0 + s];
  anB[1] = an[C0 + 16 + s];

  f32x4 acc[2][2];
#pragma unroll
  for (int i = 0; i < 2; ++i)
#pragma unroll
    for (int j = 0; j < 2; ++j)
      acc[i][j] = (f32x4){0.f, 0.f, 0.f, 0.f};

#define MFMASET(A_, B_)                                               \
  do {                                                                \
    __builtin_amdgcn_s_setprio(1);                                    \
    _Pragma("unroll")                                                 \
    for (int mi_ = 0; mi_ < 2; ++mi_)                                 \
      _Pragma("unroll")                                               \
      for (int mj_ = 0; mj_ < 2; ++mj_)                               \
        acc[mi_][mj_] = __builtin_amdgcn_mfma_f32_16x16x32_fp8_fp8(   \
            A_[mi_].x, B_[mj_].x, acc[mi_][mj_], 0, 0, 0);            \
    _Pragma("unroll")                                                 \
    for (int mi_ = 0; mi_ < 2; ++mi_)                                 \
      _Pragma("unroll")                                               \
      for (int mj_ = 0; mj_ < 2; ++mj_)                               \
        acc[mi_][mj_] = __builtin_amdgcn_mfma_f32_16x16x32_fp8_fp8(   \
            A_[mi_].y, B_[mj_].y, acc[mi_][mj_], 0, 0, 0);            \
    __builtin_amdgcn_s_setprio(0);                                    \
  } while (0)

  {
    const char* qA0 = f8p + ((size_t)(R0 >> 4) << 13) + lane * 16;
    const char* qA1 = qA0 + 8192;
    const char* qB0 = f8p + ((size_t)(C0 >> 4) << 13) + lane * 16;
    const char* qB1 = qB0 + 8192;
    longlong2 Ea[2], Eb[2], Oa[2], Ob[2];
    Ea[0] = *(const longlong2*)qA0; Ea[1] = *(const longlong2*)qA1;
    Eb[0] = *(const longlong2*)qB0; Eb[1] = *(const longlong2*)qB1;
#pragma unroll 1
    for (int it = 0; it < 4; ++it) {
      Oa[0] = *(const longlong2*)(qA0 + 1024); Oa[1] = *(const longlong2*)(qA1 + 1024);
      Ob[0] = *(const longlong2*)(qB0 + 1024); Ob[1] = *(const longlong2*)(qB1 + 1024);
      MFMASET(Ea, Eb);                  // compute even kp
      if (it < 3) {
        Ea[0] = *(const longlong2*)(qA0 + 2048); Ea[1] = *(const longlong2*)(qA1 + 2048);
        Eb[0] = *(const longlong2*)(qB0 + 2048); Eb[1] = *(const longlong2*)(qB1 + 2048);
      }
      MFMASET(Oa, Ob);                  // compute odd kp
      qA0 += 2048; qA1 += 2048; qB0 += 2048; qB1 += 2048;
    }
  }
#undef MFMASET

  // Epilogue. C/D layout (16x16x32): col=lane&15, row=(lane>>4)*4+reg.
  bool mirror = self && (ti > tj);
  bool diag = self && (ti == tj);
  float blockAcc = 0.f;
  float colAcc[2] = {0.f, 0.f};
#pragma unroll
  for (int mi = 0; mi < 2; ++mi) {
#pragma unroll
    for (int rg = 0; rg < 4; ++rg) {
      int rl = mi * 16 + q * 4 + rg;
      float aA = anA[mi][rg];
      float rowAcc = 0.f;
#pragma unroll
      for (int mj = 0; mj < 2; ++mj) {
        int cl = mj * 16 + s;
        float g = acc[mi][mj][rg];
        float d2 = fmaxf(aA + anB[mj] - g * INV_2S2, 0.f);
        if (diag && rl == cl) d2 = 0.f;  // exact diagonal
        float e1 = __expf(-0.05f * d2);
        float e2 = e1 * e1, e4 = e2 * e2, e8 = e4 * e4, e16 = e8 * e8;
        blockAcc += e1 + e2 + e4 + e8 + e16;
        if (self) {
          float ek = __expf(-12.5f * d2);  // KDE: 1/(2*0.2^2)
          rowAcc += ek;
          if (mirror) colAcc[mj] += ek;
        }
      }
      if (self) {
        rowAcc += __shfl_xor(rowAcc, 1);
        rowAcc += __shfl_xor(rowAcc, 2);
        rowAcc += __shfl_xor(rowAcc, 4);
        rowAcc += __shfl_xor(rowAcc, 8);
        if (s == 0) rs_part[(size_t)(R0 + rl) * 64 + tj] = rowAcc;
      }
    }
  }
  if (mirror) {
#pragma unroll
    for (int mj = 0; mj < 2; ++mj) {
      float v = colAcc[mj];
      v += __shfl_xor(v, 16);
      v += __shfl_xor(v, 32);
      if (q == 0)
        rs_part[(size_t)(C0 + mj * 16 + s) * 64 + ti] = v;
    }
    blockAcc *= 2.f;  // mirror tile counted once
  }
#pragma unroll
  for (int o = 1; o < 64; o <<= 1) blockAcc += __shfl_xor(blockAcc, o);
  // block-level reduce: all 4 waves of a gram block share Sidx
  if (lane == 0) bacc[wave] = blockAcc;
  __syncthreads();
  if (t == 0) atomicAdd(&S[Sidx], bacc[0] + bacc[1] + bacc[2] + bacc[3]);
}

// K2: bnout (blocks 0..97, 1024 thr) + per-class KDE weight & affinity
// (blocks 98..104). aff zeroed in k_gram.
__global__ __launch_bounds__(1024) void k_final(const float* __restrict__ logits,
                                                const float* __restrict__ S1,
                                                const float* __restrict__ S2,
                                                const float* __restrict__ gamma,
                                                const float* __restrict__ beta,
                                                const float* __restrict__ rs_part,
                                                const float* __restrict__ S,
                                                float* __restrict__ out) {
  int b = blockIdx.x, t = threadIdx.x;
  if (b < 98) {
    int idx = b * 1024 + t;  // 98*1024 = 100352 exactly
    int row = idx / 7;
    int c = idx - row * 7;
    float mu = S1[c] * (1.f / 14336.f);
    float var = S2[c] * (1.f / 14336.f) - mu * mu;
    out[idx] = gamma[c] * (logits[idx] - mu) * rsqrtf(var + 1e-5f) + beta[c];
    return;
  }
  int c = b - 98;
  // log_norm = -256*ln(2*pi*0.04) - ln(2048)
  const float LOG_NORM = 345.9110632f;
  float v = 0.f;
  for (int i = t; i < M_CLS; i += 1024) {
    const float4* rp = (const float4*)(rs_part + (size_t)(c * M_CLS + i) * 64);
    float rsum = 0.f;
#pragma unroll
    for (int jj = 0; jj < 16; ++jj) {
      float4 x = rp[jj];
      rsum += x.x + x.y + x.z + x.w;
    }
    v += 1.f / (logf(rsum) + LOG_NORM);
  }
#pragma unroll
  for (int o = 1; o < 64; o <<= 1) v += __shfl_xor(v, o);
  __shared__ float r[16];
  if ((t & 63) == 0) r[t >> 6] = v;
  __syncthreads();
  if (t == 0) {
    float vs = 0.f;
#pragma unroll
    for (int w = 0; w < 16; ++w) vs += r[w];
    float w = 1.f / (vs + 1e-5f);
    const float inv_m2 = 1.0f / ((float)M_CLS * (float)M_CLS);
    float Ssrc = S[c];
    float Stgt = (c > 0) ? S[0] : S[1];
    float X    = (c > 0) ? S[6 + c] : S[7];  // cross Sidx 7+p is (p+1,0); X01==X10
    float mmd = (Ssrc + Stgt - 2.f * X) * inv_m2;
    atomicAdd(&out[100352], -mmd * w);
  }
}

extern "C" void kernel_launch(void* const* d_in, const int* in_sizes, int n_in,
                              void* d_out, int out_size, void* d_ws, size_t ws_size,
                              hipStream_t stream) {
  const float* fea   = (const float*)d_in[0];
  const float* W_fc  = (const float*)d_in[1];
  const float* gamma = (const float*)d_in[2];
  const float* beta  = (const float*)d_in[3];
  float* out = (float*)d_out;

  char* ws = (char*)d_ws;
  char* f8p = ws;                                // packed fp8 image: 7,340,032 B
  float* fbase   = (float*)(ws + 7340032);
  float* an      = fbase;                        // 14336
  float* logits  = fbase + 14336;                // 100352
  float* zb      = fbase + 114688;               // 64-float zero block
  float* S1      = zb;                           //   [0..6]
  float* S2      = zb + 7;                       //   [7..13]
  float* S       = zb + 16;                      //   [16..28] (13 used)
  float* rs_part = fbase + 114752;               // 14336*64 row-major (fully written)

  k_prep <<<896,   256, 0, stream>>>(fea, W_fc, f8p, an, logits, zb);
  k_gram <<<10048, 256, 0, stream>>>(f8p, an, logits, S, rs_part, S1, S2,
                                     out + 100352);
  k_final<<<105,  1024, 0, stream>>>(logits, S1, S2, gamma, beta, rs_part, S, out);
}

// Round 7
// 195.366 us; speedup vs baseline: 1.2599x; 1.2320x over previous
//
#include <hip/hip_runtime.h>

#define B_ROWS 14336
#define D_DIM  512
#define C_CLS  7
#define M_CLS  2048

typedef __attribute__((ext_vector_type(4))) float f32x4;

// fp8 scale: fea*64 -> sigma~3.2 in e4m3 range; Gram scaled by 4096
#define FP8_SCALE 64.0f
#define INV_2S2   (2.0f / 4096.0f)

typedef const __attribute__((address_space(1))) char gchar_t;
typedef __attribute__((address_space(3))) char lchar_t;

__device__ __forceinline__ void gload16(const char* g, char* l) {
  // async global->LDS DMA, 16B/lane, dest = wave-uniform base + lane*16
  __builtin_amdgcn_global_load_lds((gchar_t*)g, (lchar_t*)l, 16, 0, 0);
}

// K0: fea->fp8 packed in fragment-order image + row norms + logits + zero zb.
// Image layout: 16B at (r16, kp, l) = byte ((r16*8 + kp)*64 + l)*16, holding
// row r16*16 + (l&15), k-bytes {kp*64 + (l>>4)*8 ..+7} (.x) and {+32..} (.y).
__global__ __launch_bounds__(256) void k_prep(const float* __restrict__ fea,
                                              const float* __restrict__ W,
                                              char* __restrict__ f8p,
                                              float* __restrict__ an,
                                              float* __restrict__ logits,
                                              float* __restrict__ zb) {  // 64 floats
  int t = threadIdx.x, wave = t >> 6, lane = t & 63;
  if (blockIdx.x == 0 && t < 64) zb[t] = 0.f;
  __shared__ char lrow[16 * 528];  // 16 rows x 512B fp8 (+16 pad)

  int r0 = blockIdx.x * 16;
#pragma unroll
  for (int k = 0; k < 4; ++k) {
    int rl = wave * 4 + k;
    int row = r0 + rl;
    const float4* fr4 = (const float4*)(fea + (size_t)row * D_DIM);
    float4 v0 = fr4[lane * 2], v1 = fr4[lane * 2 + 1];

    float p[8];
#pragma unroll
    for (int c = 0; c < 7; ++c) {
      const float4* w4 = (const float4*)(W + c * D_DIM);
      float4 q0 = w4[lane * 2], q1 = w4[lane * 2 + 1];
      p[c] = v0.x * q0.x + v0.y * q0.y + v0.z * q0.z + v0.w * q0.w +
             v1.x * q1.x + v1.y * q1.y + v1.z * q1.z + v1.w * q1.w;
    }
    p[7] = v0.x * v0.x + v0.y * v0.y + v0.z * v0.z + v0.w * v0.w +
           v1.x * v1.x + v1.y * v1.y + v1.z * v1.z + v1.w * v1.w;

#pragma unroll
    for (int c = 0; c < 8; ++c) {
      p[c] += __shfl_xor(p[c], 1);
      p[c] += __shfl_xor(p[c], 2);
      p[c] += __shfl_xor(p[c], 4);
    }
    int v = lane & 7;
    float y = p[0];
    y = (v == 1) ? p[1] : y;
    y = (v == 2) ? p[2] : y;
    y = (v == 3) ? p[3] : y;
    y = (v == 4) ? p[4] : y;
    y = (v == 5) ? p[5] : y;
    y = (v == 6) ? p[6] : y;
    y = (v == 7) ? p[7] : y;
    y += __shfl_xor(y, 8);
    y += __shfl_xor(y, 16);
    y += __shfl_xor(y, 32);
    if (lane < 7) logits[row * 7 + lane] = y;
    else if (lane == 7) an[row] = y;

    int w0 = __builtin_amdgcn_cvt_pk_fp8_f32(v0.x * FP8_SCALE, v0.y * FP8_SCALE, 0, 0);
    w0     = __builtin_amdgcn_cvt_pk_fp8_f32(v0.z * FP8_SCALE, v0.w * FP8_SCALE, w0, 1);
    int w1 = __builtin_amdgcn_cvt_pk_fp8_f32(v1.x * FP8_SCALE, v1.y * FP8_SCALE, 0, 0);
    w1     = __builtin_amdgcn_cvt_pk_fp8_f32(v1.z * FP8_SCALE, v1.w * FP8_SCALE, w1, 1);
    *(int2*)&lrow[rl * 528 + lane * 8] = make_int2(w0, w1);
  }
  __syncthreads();
  int4* outp = (int4*)f8p + (size_t)blockIdx.x * 512;
#pragma unroll
  for (int pi = 0; pi < 2; ++pi) {
    int idx = pi * 256 + t;          // [0,512) = (kp, l)
    int kp = idx >> 6, l = idx & 63;
    int sr = l & 15, qk = l >> 4;
    int2 lo = *(const int2*)&lrow[sr * 528 + kp * 64 + qk * 8];
    int2 hi = *(const int2*)&lrow[sr * 528 + kp * 64 + 32 + qk * 8];
    outp[idx] = make_int4(lo.x, lo.y, hi.x, hi.y);
  }
}

// K1 v7: 256x256 block tile, 8 waves (2M x 4N, each wave 128x64), BK=64
// (one image kp), double-buffered LDS (A,B = 4x16KB), staged via
// global_load_lds. T3 minimal 2-phase: per K-tile {STAGE next -> buf^1;
// 12 ds_read_b128 from buf; 64 MFMA; one barrier}. 64 MFMA/wave of compute
// per barrier (4x round-0) covers the DMA drain; staging traffic 167 MB
// total (vs 1.25 GB reg-direct) so the L1/TCP path is off the critical path.
// Blocks: 0..251 self (cls = b/36, tri 36: ti>=tj), 252..635 cross
// (p = (b-252)>>6, 8x8), 636..642 BN-stat blocks (8 wave-jobs each).
// rs_part: 48 slots/row: direct tj*4+wc in [0,4*bi+4); mirror 32+ti*2+wr
// in [34+2bi,48). Unwritten slots are never read by k_final.
__global__ __launch_bounds__(512, 2) void k_gram(const char* __restrict__ f8p,
                                                 const float* __restrict__ an,
                                                 const float* __restrict__ logits,
                                                 float* __restrict__ S,
                                                 float* __restrict__ rs_part,
                                                 float* __restrict__ S1,
                                                 float* __restrict__ S2,
                                                 float* __restrict__ aff) {
  int b = blockIdx.x;
  int t = threadIdx.x, lane = t & 63, wave = t >> 6;
  if (b == 0 && t == 0) aff[0] = 0.f;

  if (b >= 636) {  // BN stats: 7 blocks x 8 waves = 56 jobs
    int idx = (b - 636) * 8 + wave;
    int c = idx >> 3, seg = idx & 7;
    int r0 = seg * 1792;
    float s1 = 0.f, s2 = 0.f;
    for (int j = lane; j < 1792; j += 64) {
      float v = logits[(size_t)(r0 + j) * 7 + c];
      s1 += v;
      s2 += v * v;
    }
#pragma unroll
    for (int o = 1; o < 64; o <<= 1) {
      s1 += __shfl_xor(s1, o);
      s2 += __shfl_xor(s2, o);
    }
    if (lane == 0) { atomicAdd(&S1[c], s1); atomicAdd(&S2[c], s2); }
    return;
  }

  __shared__ char ldsA[2][16384];
  __shared__ char ldsB[2][16384];
  __shared__ float bacc[8];

  int cls1, cls2, ti, tj, Sidx;
  bool self;
  if (b < 252) {
    int cls = b / 36, t36 = b - cls * 36;
    int a = 0, r = t36;
    while (r > a) { r -= a + 1; ++a; }  // <=8 iters: t36 = a(a+1)/2 + r
    ti = a; tj = r;                     // tj <= ti
    cls1 = cls; cls2 = cls; Sidx = cls; self = true;
  } else {
    int e = b - 252;
    int p = e >> 6, t64 = e & 63;
    ti = t64 >> 3; tj = t64 & 7;
    cls1 = p + 1; cls2 = 0; Sidx = 7 + p; self = false;
  }
  int R0 = cls1 * 2048 + ti * 256;
  int C0 = cls2 * 2048 + tj * 256;

  // staging: wave stages chunks {2w, 2w+1} of A and B per K-tile
  const char* gA0 = f8p + ((size_t)(R0 >> 4) + wave * 2)     * 8192 + lane * 16;
  const char* gA1 = f8p + ((size_t)(R0 >> 4) + wave * 2 + 1) * 8192 + lane * 16;
  const char* gB0 = f8p + ((size_t)(C0 >> 4) + wave * 2)     * 8192 + lane * 16;
  const char* gB1 = f8p + ((size_t)(C0 >> 4) + wave * 2 + 1) * 8192 + lane * 16;

#define STAGE(kt_, bf_)                                                      \
  do {                                                                       \
    gload16(gA0 + (kt_) * 1024, &ldsA[bf_][(wave * 2) * 1024 + lane * 16]);  \
    gload16(gA1 + (kt_) * 1024, &ldsA[bf_][(wave * 2 + 1) * 1024 + lane * 16]); \
    gload16(gB0 + (kt_) * 1024, &ldsB[bf_][(wave * 2) * 1024 + lane * 16]);  \
    gload16(gB1 + (kt_) * 1024, &ldsB[bf_][(wave * 2 + 1) * 1024 + lane * 16]); \
  } while (0)

  int wr = wave >> 2, wc = wave & 3;   // 2M x 4N wave grid
  int q = lane >> 4, s = lane & 15;

  f32x4 acc[8][4];
#pragma unroll
  for (int i = 0; i < 8; ++i)
#pragma unroll
    for (int j = 0; j < 4; ++j)
      acc[i][j] = (f32x4){0.f, 0.f, 0.f, 0.f};

  STAGE(0, 0);
  __syncthreads();  // drains DMA (compiler emits vmcnt(0) before barrier)

#pragma unroll 1
  for (int kt = 0; kt < 8; ++kt) {
    int cur = kt & 1;
    if (kt < 7) STAGE(kt + 1, cur ^ 1);  // async; drained by END barrier
    const char* LA = &ldsA[cur][(wr * 8) * 1024 + lane * 16];
    const char* LB = &ldsB[cur][(wc * 4) * 1024 + lane * 16];
    longlong2 a_[8], bb_[4];
#pragma unroll
    for (int i = 0; i < 8; ++i) a_[i] = *(const longlong2*)(LA + i * 1024);
#pragma unroll
    for (int j = 0; j < 4; ++j) bb_[j] = *(const longlong2*)(LB + j * 1024);
    __builtin_amdgcn_s_setprio(1);
#pragma unroll
    for (int i = 0; i < 8; ++i)
#pragma unroll
      for (int j = 0; j < 4; ++j)
        acc[i][j] = __builtin_amdgcn_mfma_f32_16x16x32_fp8_fp8(
            a_[i].x, bb_[j].x, acc[i][j], 0, 0, 0);
#pragma unroll
    for (int i = 0; i < 8; ++i)
#pragma unroll
      for (int j = 0; j < 4; ++j)
        acc[i][j] = __builtin_amdgcn_mfma_f32_16x16x32_fp8_fp8(
            a_[i].y, bb_[j].y, acc[i][j], 0, 0, 0);
    __builtin_amdgcn_s_setprio(0);
    __syncthreads();  // one barrier per K-tile: drains next-buf DMA,
                      // and protects cur from being overwritten next iter
  }
#undef STAGE

  // Epilogue. C/D (16x16x32): col=lane&15, row=(lane>>4)*4+reg.
  // Element (i,rg,j): row rl = wr*128+i*16+q*4+rg, col cl = wc*64+j*16+s.
  bool dg = self && (ti == tj);
  bool mirror = self && (ti > tj);
  float blockAcc = 0.f;
  float colAcc[4] = {0.f, 0.f, 0.f, 0.f};
  float anB_[4];
#pragma unroll
  for (int j = 0; j < 4; ++j) anB_[j] = an[C0 + wc * 64 + j * 16 + s];

#pragma unroll
  for (int i = 0; i < 8; ++i) {
    f32x4 anA_ = *(const f32x4*)&an[R0 + wr * 128 + i * 16 + q * 4];
#pragma unroll
    for (int rg = 0; rg < 4; ++rg) {
      int rl = wr * 128 + i * 16 + q * 4 + rg;
      float aA = anA_[rg];
      float rowAcc = 0.f;
#pragma unroll
      for (int j = 0; j < 4; ++j) {
        int cl = wc * 64 + j * 16 + s;
        float g = acc[i][j][rg];
        float d2 = fmaxf(aA + anB_[j] - g * INV_2S2, 0.f);
        if (dg && rl == cl) d2 = 0.f;  // exact diagonal
        float e1 = __expf(-0.05f * d2);
        float e2 = e1 * e1, e4 = e2 * e2, e8 = e4 * e4, e16 = e8 * e8;
        blockAcc += e1 + e2 + e4 + e8 + e16;
        if (self) {
          float ek = __expf(-12.5f * d2);  // KDE: 1/(2*0.2^2)
          rowAcc += ek;
          if (mirror) colAcc[j] += ek;
        }
      }
      if (self) {
        rowAcc += __shfl_xor(rowAcc, 1);
        rowAcc += __shfl_xor(rowAcc, 2);
        rowAcc += __shfl_xor(rowAcc, 4);
        rowAcc += __shfl_xor(rowAcc, 8);
        if (s == 0)
          rs_part[(size_t)(R0 + rl) * 48 + tj * 4 + wc] = rowAcc;
      }
    }
  }
  if (mirror) {
#pragma unroll
    for (int j = 0; j < 4; ++j) {
      float v = colAcc[j];
      v += __shfl_xor(v, 16);
      v += __shfl_xor(v, 32);
      if (q == 0)
        rs_part[(size_t)(C0 + wc * 64 + j * 16 + s) * 48 + 32 + ti * 2 + wr] = v;
    }
    blockAcc *= 2.f;  // mirror tile counted once
  }
#pragma unroll
  for (int o = 1; o < 64; o <<= 1) blockAcc += __shfl_xor(blockAcc, o);
  if (lane == 0) bacc[wave] = blockAcc;
  __syncthreads();
  if (t == 0) {
    float sB = 0.f;
#pragma unroll
    for (int w = 0; w < 8; ++w) sB += bacc[w];
    atomicAdd(&S[Sidx], sB);
  }
}

// K2: bnout (blocks 0..97, 1024 thr) + per-class KDE weight & affinity
// (blocks 98..104). Reads only the valid rs_part slots per block-row bi:
// direct [0, 4bi+4), mirror [34+2bi, 48).
__global__ __launch_bounds__(1024) void k_final(const float* __restrict__ logits,
                                                const float* __restrict__ S1,
                                                const float* __restrict__ S2,
                                                const float* __restrict__ gamma,
                                                const float* __restrict__ beta,
                                                const float* __restrict__ rs_part,
                                                const float* __restrict__ S,
                                                float* __restrict__ out) {
  int b = blockIdx.x, t = threadIdx.x;
  if (b < 98) {
    int idx = b * 1024 + t;  // 98*1024 = 100352 exactly
    int row = idx / 7;
    int c = idx - row * 7;
    float mu = S1[c] * (1.f / 14336.f);
    float var = S2[c] * (1.f / 14336.f) - mu * mu;
    out[idx] = gamma[c] * (logits[idx] - mu) * rsqrtf(var + 1e-5f) + beta[c];
    return;
  }
  int c = b - 98;
  // log_norm = -256*ln(2*pi*0.04) - ln(2048)
  const float LOG_NORM = 345.9110632f;
  float v = 0.f;
  for (int i = t; i < M_CLS; i += 1024) {
    int bi = i >> 8;
    const float* rp = rs_part + (size_t)(c * M_CLS + i) * 48;
    float rsum = 0.f;
    int nd = 4 * bi + 4;
    for (int k = 0; k < nd; ++k) rsum += rp[k];
    for (int k = 34 + 2 * bi; k < 48; ++k) rsum += rp[k];
    v += 1.f / (logf(rsum) + LOG_NORM);
  }
#pragma unroll
  for (int o = 1; o < 64; o <<= 1) v += __shfl_xor(v, o);
  __shared__ float r[16];
  if ((t & 63) == 0) r[t >> 6] = v;
  __syncthreads();
  if (t == 0) {
    float vs = 0.f;
#pragma unroll
    for (int w = 0; w < 16; ++w) vs += r[w];
    float w = 1.f / (vs + 1e-5f);
    const float inv_m2 = 1.0f / ((float)M_CLS * (float)M_CLS);
    float Ssrc = S[c];
    float Stgt = (c > 0) ? S[0] : S[1];
    float X    = (c > 0) ? S[6 + c] : S[7];  // cross Sidx 7+p is (p+1,0)
    float mmd = (Ssrc + Stgt - 2.f * X) * inv_m2;
    atomicAdd(&out[100352], -mmd * w);
  }
}

extern "C" void kernel_launch(void* const* d_in, const int* in_sizes, int n_in,
                              void* d_out, int out_size, void* d_ws, size_t ws_size,
                              hipStream_t stream) {
  const float* fea   = (const float*)d_in[0];
  const float* W_fc  = (const float*)d_in[1];
  const float* gamma = (const float*)d_in[2];
  const float* beta  = (const float*)d_in[3];
  float* out = (float*)d_out;

  char* ws = (char*)d_ws;
  char* f8p = ws;                                // packed fp8 image: 7,340,032 B
  float* fbase   = (float*)(ws + 7340032);
  float* an      = fbase;                        // 14336
  float* logits  = fbase + 14336;                // 100352
  float* zb      = fbase + 114688;               // 64-float zero block
  float* S1      = zb;                           //   [0..6]
  float* S2      = zb + 7;                       //   [7..13]
  float* S       = zb + 16;                      //   [16..28] (13 used)
  float* rs_part = fbase + 114752;               // 14336*48 (valid slots only)

  k_prep <<<896, 256, 0, stream>>>(fea, W_fc, f8p, an, logits, zb);
  k_gram <<<643, 512, 0, stream>>>(f8p, an, logits, S, rs_part, S1, S2,
                                   out + 100352);
  k_final<<<105, 1024, 0, stream>>>(logits, S1, S2, gamma, beta, rs_part, S, out);
}